// Round 5
// baseline (187.805 us; speedup 1.0000x reference)
//
#include <hip/hip_runtime.h>

// Round 4: latency attack.
// - attn: 16 q-rows/wave (4096 waves, 4 blocks/CU), explicit K/V register
//   prefetch, zero LDS / zero barriers (S^T trick keeps P register-local).
// - GEMMs: barrier-free K-loops, MFMA fragments loaded straight from global
//   (W is L2-resident); LDS only for qkv scatter epilogue.
// Pipeline: cvt_bf16 -> qkv_mfma -> attn_stream -> out_mfma.

#define SEQ 2048
#define BATCH 4
#define NHEADS 8
#define HDIM 32
#define DIMC 256
#define SCALE_LOG2E 0.09016844005556021f  // (1/16)*log2(e)

typedef __attribute__((ext_vector_type(8))) short short8;
typedef __attribute__((ext_vector_type(4))) float f32x4;

union BF8 { unsigned u[4]; short8 s8; };

__device__ __forceinline__ unsigned pk2bf(float a, float b) {
    union { float f; unsigned u; } ua, ub;
    ua.f = a; ub.f = b;
    return __builtin_amdgcn_perm(ub.u + 0x8000u, ua.u + 0x8000u, 0x07060302u);
}
__device__ __forceinline__ short f2bf(float a) {
    union { float f; unsigned u; } x; x.f = a;
    return (short)((x.u + 0x8000u) >> 16);
}

#define NX (BATCH * SEQ * DIMC)     // 2097152
#define NQW (3 * DIMC * DIMC)       // 196608
#define NOW (DIMC * DIMC)           // 65536

__global__ __launch_bounds__(256) void cvt_bf16(const float* __restrict__ x,
                                                const float* __restrict__ wq,
                                                const float* __restrict__ wo,
                                                short* __restrict__ xb,
                                                short* __restrict__ wqb,
                                                short* __restrict__ wob) {
    int i = (blockIdx.x * 256 + threadIdx.x) * 4;
    const float* src;
    short* dst;
    int off;
    if (i < NX) { src = x; dst = xb; off = i; }
    else if (i < NX + NQW) { src = wq; dst = wqb; off = i - NX; }
    else { src = wo; dst = wob; off = i - NX - NQW; }
    float4 v = *(const float4*)&src[off];
    uint2 p;
    p.x = pk2bf(v.x, v.y);
    p.y = pk2bf(v.z, v.w);
    *(uint2*)&dst[off] = p;
}

// ---------------------------------------------------------------------------
// QKV GEMM: C[8192][768] = Xb.Wb^T + b. 128x64 tile, grid (12,64)=768 blocks.
// Wave w: rows w*32..+32 (2 mt) x 64 n (4 nt). Fragments straight from
// global, no K-loop LDS/barriers. LDS-staged coalesced scatter epilogue:
// Q (pre-scaled SCALE*log2e)/K -> [bh][tok][d]; V -> [bh][d][tok].
// ---------------------------------------------------------------------------
__global__ __launch_bounds__(256, 4) void qkv_mfma(const short* __restrict__ Xb,
                                                   const short* __restrict__ Wb,
                                                   const float* __restrict__ bias,
                                                   short* __restrict__ Q,
                                                   short* __restrict__ Kd,
                                                   short* __restrict__ V) {
    __shared__ __align__(16) short Cs[128 * 72];  // Q/K: [tok][72]; V-T: [col][136]

    const int m0 = blockIdx.y * 128, bx = blockIdx.x;
    const int tid = threadIdx.x;
    const int w = tid >> 6, lane = tid & 63;
    const int m = lane & 15, g = lane >> 4;

    f32x4 acc[2][4] = {};

    const short* arow0 = Xb + (size_t)(m0 + w * 32 + m) * DIMC + g * 8;
    const short* brow0 = Wb + (size_t)(bx * 64 + m) * DIMC + g * 8;

#pragma unroll 2
    for (int kt = 0; kt < DIMC; kt += 32) {
        short8 af[2], bf[4];
#pragma unroll
        for (int mt = 0; mt < 2; mt++)
            af[mt] = *(const short8*)(arow0 + mt * 16 * DIMC + kt);
#pragma unroll
        for (int nt = 0; nt < 4; nt++)
            bf[nt] = *(const short8*)(brow0 + nt * 16 * DIMC + kt);
#pragma unroll
        for (int mt = 0; mt < 2; mt++)
#pragma unroll
            for (int nt = 0; nt < 4; nt++)
                acc[mt][nt] = __builtin_amdgcn_mfma_f32_16x16x32_bf16(af[mt], bf[nt], acc[mt][nt], 0, 0, 0);
    }

    const int which = bx >> 2;            // 0=Q 1=K 2=V
    const int h0 = (bx & 3) * 2;          // 2 heads per 64-col tile
    const int bidx = blockIdx.y >> 4;
    const int ntok0 = (blockIdx.y & 15) * 128;
    float bv[4];
#pragma unroll
    for (int nt = 0; nt < 4; nt++) bv[nt] = bias[bx * 64 + nt * 16 + m];

    if (which != 2) {
        const float qs = (which == 0) ? SCALE_LOG2E : 1.0f;
#pragma unroll
        for (int mt = 0; mt < 2; mt++)
#pragma unroll
            for (int nt = 0; nt < 4; nt++)
#pragma unroll
                for (int r = 0; r < 4; r++)
                    Cs[(w * 32 + mt * 16 + g * 4 + r) * 72 + nt * 16 + m] =
                        f2bf((acc[mt][nt][r] + bv[nt]) * qs);
        __syncthreads();
        short* dst = (which == 0) ? Q : Kd;
        const int tok = tid >> 1, d0 = (tid & 1) * 16;
#pragma unroll
        for (int hh = 0; hh < 2; hh++) {
            size_t o = ((size_t)((bidx * NHEADS + h0 + hh) * SEQ) + ntok0 + tok) * HDIM + d0;
            *(short8*)&dst[o] = *(const short8*)&Cs[tok * 72 + hh * 32 + d0];
            *(short8*)&dst[o + 8] = *(const short8*)&Cs[tok * 72 + hh * 32 + d0 + 8];
        }
    } else {
        // transposed staging: Cs[col][tok], stride 136
#pragma unroll
        for (int mt = 0; mt < 2; mt++)
#pragma unroll
            for (int nt = 0; nt < 4; nt++) {
                uint2 p;
                p.x = pk2bf(acc[mt][nt][0] + bv[nt], acc[mt][nt][1] + bv[nt]);
                p.y = pk2bf(acc[mt][nt][2] + bv[nt], acc[mt][nt][3] + bv[nt]);
                *(uint2*)&Cs[(nt * 16 + m) * 136 + w * 32 + mt * 16 + g * 4] = p;
            }
        __syncthreads();
        const int col = tid >> 2, t0 = (tid & 3) * 32;
        const int hh = col >> 5, d = col & 31;
        size_t o = ((size_t)((bidx * NHEADS + h0 + hh) * HDIM) + d) * SEQ + ntok0 + t0;
#pragma unroll
        for (int c2 = 0; c2 < 4; c2++)
            *(short8*)&V[o + c2 * 8] = *(const short8*)&Cs[col * 136 + t0 + c2 * 8];
    }
}

// ---------------------------------------------------------------------------
// Streaming flash attention: no LDS/barriers. grid=(32 qtiles, 32 bh),
// 4 waves x 16 q-rows. Explicit next-tile K/V register prefetch.
// S^T = K.Q^T with sigma-permuted K rows => P register-local in PV A-layout.
// ---------------------------------------------------------------------------
__global__ __launch_bounds__(256, 4) void attn_stream(const short* __restrict__ Q,
                                                      const short* __restrict__ K,
                                                      const short* __restrict__ V,  // [bh][d][tok]
                                                      short* __restrict__ Zb) {
    const int bh = blockIdx.y;
    const int b = bh >> 3, h = bh & 7;
    const int q0 = blockIdx.x * 64;
    const short* qb = Q + (size_t)bh * SEQ * HDIM;
    const short* kb = K + (size_t)bh * SEQ * HDIM;
    const short* vb = V + (size_t)bh * HDIM * SEQ;
    const int tid = threadIdx.x;
    const int w = tid >> 6, lane = tid & 63;
    const int m = lane & 15, g = lane >> 4;

    const short8 qf = *(const short8*)(qb + (size_t)(q0 + w * 16 + m) * HDIM + g * 8);

    // sigma(t, m): K-row permutation so P exits S^T in PV A-layout per-lane.
    int koff[4];
#pragma unroll
    for (int t = 0; t < 4; t++) {
        int row = 32 * (t >> 1) + ((m >> 2) << 3) + ((t & 1) << 2) + (m & 3);
        koff[t] = row * HDIM + g * 8;
    }
    const int voff0 = m * SEQ + g * 8;
    const int voff1 = (m + 16) * SEQ + g * 8;

    f32x4 o0 = {0.f, 0.f, 0.f, 0.f};
    f32x4 o1 = {0.f, 0.f, 0.f, 0.f};
    f32x4 ol = {0.f, 0.f, 0.f, 0.f};
    const short8 ones = {0x3F80, 0x3F80, 0x3F80, 0x3F80, 0x3F80, 0x3F80, 0x3F80, 0x3F80};

    short8 kf[4], vf[4];
#pragma unroll
    for (int t = 0; t < 4; t++) kf[t] = *(const short8*)(kb + koff[t]);
    vf[0] = *(const short8*)(vb + voff0);
    vf[1] = *(const short8*)(vb + voff1);
    vf[2] = *(const short8*)(vb + voff0 + 32);
    vf[3] = *(const short8*)(vb + voff1 + 32);

    for (int k0 = 0; k0 < SEQ; k0 += 64) {
        const int kn = (k0 + 64 < SEQ) ? k0 + 64 : 0;  // wrap: harmless reload
        short8 kfn[4], vfn[4];
#pragma unroll
        for (int t = 0; t < 4; t++)
            kfn[t] = *(const short8*)(kb + (size_t)kn * HDIM + koff[t]);
        vfn[0] = *(const short8*)(vb + voff0 + kn);
        vfn[1] = *(const short8*)(vb + voff1 + kn);
        vfn[2] = *(const short8*)(vb + voff0 + kn + 32);
        vfn[3] = *(const short8*)(vb + voff1 + kn + 32);

        f32x4 st[4];
#pragma unroll
        for (int t = 0; t < 4; t++) {
            f32x4 z4 = {0.f, 0.f, 0.f, 0.f};
            st[t] = __builtin_amdgcn_mfma_f32_16x16x32_bf16(kf[t], qf, z4, 0, 0, 0);
        }

        BF8 a0, a1;
        a0.u[0] = pk2bf(__builtin_amdgcn_exp2f(st[0][0]), __builtin_amdgcn_exp2f(st[0][1]));
        a0.u[1] = pk2bf(__builtin_amdgcn_exp2f(st[0][2]), __builtin_amdgcn_exp2f(st[0][3]));
        a0.u[2] = pk2bf(__builtin_amdgcn_exp2f(st[1][0]), __builtin_amdgcn_exp2f(st[1][1]));
        a0.u[3] = pk2bf(__builtin_amdgcn_exp2f(st[1][2]), __builtin_amdgcn_exp2f(st[1][3]));
        a1.u[0] = pk2bf(__builtin_amdgcn_exp2f(st[2][0]), __builtin_amdgcn_exp2f(st[2][1]));
        a1.u[1] = pk2bf(__builtin_amdgcn_exp2f(st[2][2]), __builtin_amdgcn_exp2f(st[2][3]));
        a1.u[2] = pk2bf(__builtin_amdgcn_exp2f(st[3][0]), __builtin_amdgcn_exp2f(st[3][1]));
        a1.u[3] = pk2bf(__builtin_amdgcn_exp2f(st[3][2]), __builtin_amdgcn_exp2f(st[3][3]));

        o0 = __builtin_amdgcn_mfma_f32_16x16x32_bf16(a0.s8, vf[0], o0, 0, 0, 0);
        o1 = __builtin_amdgcn_mfma_f32_16x16x32_bf16(a0.s8, vf[1], o1, 0, 0, 0);
        ol = __builtin_amdgcn_mfma_f32_16x16x32_bf16(a0.s8, ones, ol, 0, 0, 0);
        o0 = __builtin_amdgcn_mfma_f32_16x16x32_bf16(a1.s8, vf[2], o0, 0, 0, 0);
        o1 = __builtin_amdgcn_mfma_f32_16x16x32_bf16(a1.s8, vf[3], o1, 0, 0, 0);
        ol = __builtin_amdgcn_mfma_f32_16x16x32_bf16(a1.s8, ones, ol, 0, 0, 0);

#pragma unroll
        for (int t = 0; t < 4; t++) { kf[t] = kfn[t]; vf[t] = vfn[t]; }
    }

#pragma unroll
    for (int r = 0; r < 4; r++) {
        float inv = __builtin_amdgcn_rcpf(ol[r]);
        int row = q0 + w * 16 + g * 4 + r;
        size_t zo = ((size_t)(b * SEQ + row)) * DIMC + h * HDIM + m;
        Zb[zo] = f2bf(o0[r] * inv);
        Zb[zo + 16] = f2bf(o1[r] * inv);
    }
}

// ---------------------------------------------------------------------------
// Out GEMM: out[8192][256] = Zb.Wob^T + b (fp32). 64x64 tile, grid (4,128).
// Barrier-free: fragments straight from global.
// ---------------------------------------------------------------------------
__global__ __launch_bounds__(256, 4) void out_mfma(const short* __restrict__ A,
                                                   const short* __restrict__ Wb,
                                                   const float* __restrict__ bias,
                                                   float* __restrict__ C) {
    const int m0 = blockIdx.y * 64, n0 = blockIdx.x * 64;
    const int tid = threadIdx.x;
    const int w = tid >> 6, lane = tid & 63;
    const int m = lane & 15, g = lane >> 4;

    f32x4 acc[4] = {};
    const short* arow = A + (size_t)(m0 + w * 16 + m) * DIMC + g * 8;
    const short* brow = Wb + (size_t)(n0 + m) * DIMC + g * 8;

#pragma unroll 2
    for (int kt = 0; kt < DIMC; kt += 32) {
        short8 af = *(const short8*)(arow + kt);
        short8 bf[4];
#pragma unroll
        for (int nt = 0; nt < 4; nt++)
            bf[nt] = *(const short8*)(brow + nt * 16 * DIMC + kt);
#pragma unroll
        for (int nt = 0; nt < 4; nt++)
            acc[nt] = __builtin_amdgcn_mfma_f32_16x16x32_bf16(af, bf[nt], acc[nt], 0, 0, 0);
    }

    float bv[4];
#pragma unroll
    for (int nt = 0; nt < 4; nt++) bv[nt] = bias[n0 + nt * 16 + m];
#pragma unroll
    for (int nt = 0; nt < 4; nt++)
#pragma unroll
        for (int r = 0; r < 4; r++)
            C[(size_t)(m0 + w * 16 + g * 4 + r) * DIMC + n0 + nt * 16 + m] = acc[nt][r] + bv[nt];
}

extern "C" void kernel_launch(void* const* d_in, const int* in_sizes, int n_in,
                              void* d_out, int out_size, void* d_ws, size_t ws_size,
                              hipStream_t stream) {
    const float* x     = (const float*)d_in[0];
    const float* w_qkv = (const float*)d_in[1];
    const float* b_qkv = (const float*)d_in[2];
    const float* w_out = (const float*)d_in[3];
    const float* b_out = (const float*)d_in[4];
    float* out = (float*)d_out;

    const size_t HSZ = (size_t)BATCH * NHEADS * SEQ * HDIM;  // 2M elems
    short* xb  = (short*)d_ws;
    short* wqb = xb + NX;
    short* wob = wqb + NQW;
    short* qw  = wob + NOW;
    short* kw  = qw + HSZ;
    short* vw  = kw + HSZ;
    short* zb  = vw + HSZ;

    cvt_bf16<<<(NX + NQW + NOW) / 1024, 256, 0, stream>>>(x, w_qkv, w_out, xb, wqb, wob);
    qkv_mfma<<<dim3(12, 64), 256, 0, stream>>>(xb, wqb, b_qkv, qw, kw, vw);
    attn_stream<<<dim3(32, 32), 256, 0, stream>>>(qw, kw, vw, zb);
    out_mfma<<<dim3(4, 128), 256, 0, stream>>>(zb, wob, b_out, out);
}

// Round 6
// 122.716 us; speedup vs baseline: 1.5304x; 1.5304x over previous
//
#include <hip/hip_runtime.h>

// Round 5: attention = LDS double-buffered, k-split-across-waves tile kernel.
// Block: 64 q-rows, KV tile 128 (16 iters). Wave w owns k-sub w*32..+32.
// K staged sigma-PERMUTED so frag reads are contiguous rows; P register-local.
// Cross-wave O/l reduce via unioned LDS epilogue. GEMMs = R3 versions.

#define SEQ 2048
#define BATCH 4
#define NHEADS 8
#define HDIM 32
#define DIMC 256
#define SCALE_LOG2E 0.09016844005556021f  // (1/16)*log2(e)

typedef __attribute__((ext_vector_type(8))) short short8;
typedef __attribute__((ext_vector_type(4))) float f32x4;

union BF8 { unsigned u[4]; short8 s8; };

__device__ __forceinline__ unsigned pk2bf(float a, float b) {
    union { float f; unsigned u; } ua, ub;
    ua.f = a; ub.f = b;
    return __builtin_amdgcn_perm(ub.u + 0x8000u, ua.u + 0x8000u, 0x07060302u);
}
__device__ __forceinline__ short f2bf(float a) {
    union { float f; unsigned u; } x; x.f = a;
    return (short)((x.u + 0x8000u) >> 16);
}

#define NX (BATCH * SEQ * DIMC)
#define NQW (3 * DIMC * DIMC)
#define NOW (DIMC * DIMC)

__global__ __launch_bounds__(256) void cvt_bf16(const float* __restrict__ x,
                                                const float* __restrict__ wq,
                                                const float* __restrict__ wo,
                                                short* __restrict__ xb,
                                                short* __restrict__ wqb,
                                                short* __restrict__ wob) {
    int i = (blockIdx.x * 256 + threadIdx.x) * 4;
    const float* src;
    short* dst;
    int off;
    if (i < NX) { src = x; dst = xb; off = i; }
    else if (i < NX + NQW) { src = wq; dst = wqb; off = i - NX; }
    else { src = wo; dst = wob; off = i - NX - NQW; }
    float4 v = *(const float4*)&src[off];
    uint2 p;
    p.x = pk2bf(v.x, v.y);
    p.y = pk2bf(v.z, v.w);
    *(uint2*)&dst[off] = p;
}

// ---------------------------------------------------------------------------
// QKV GEMM (R3 version): 128x128 tile, BK=64, LDS-staged, coalesced scatter.
// ---------------------------------------------------------------------------
__global__ __launch_bounds__(256) void qkv_mfma(const short* __restrict__ Xb,
                                                const short* __restrict__ Wb,
                                                const float* __restrict__ bias,
                                                short* __restrict__ Q,
                                                short* __restrict__ Kd,
                                                short* __restrict__ V) {
    __shared__ __align__(16) union SM {
        struct { short A[128][72]; short B[128][72]; } ab;
        short C[128][136];
    } sm;
    const int m0 = blockIdx.y * 128, bx = blockIdx.x;
    const int tid = threadIdx.x;
    const int w = tid >> 6, lane = tid & 63;
    const int m = lane & 15, g = lane >> 4;
    const int wr = w >> 1, wc = w & 1;
    const int srow = tid >> 1, scol = (tid & 1) * 32;

    f32x4 acc[4][4] = {};

    for (int kt = 0; kt < DIMC; kt += 64) {
        short8 a8[4], b8[4];
#pragma unroll
        for (int i = 0; i < 4; i++) {
            a8[i] = *(const short8*)&Xb[(size_t)(m0 + srow) * DIMC + kt + scol + i * 8];
            b8[i] = *(const short8*)&Wb[(size_t)(bx * 128 + srow) * DIMC + kt + scol + i * 8];
        }
        __syncthreads();
#pragma unroll
        for (int i = 0; i < 4; i++) {
            *(short8*)&sm.ab.A[srow][scol + i * 8] = a8[i];
            *(short8*)&sm.ab.B[srow][scol + i * 8] = b8[i];
        }
        __syncthreads();
#pragma unroll
        for (int kk = 0; kk < 2; kk++) {
            short8 af[4], bf[4];
#pragma unroll
            for (int mt = 0; mt < 4; mt++) af[mt] = *(const short8*)&sm.ab.A[wr * 64 + mt * 16 + m][kk * 32 + g * 8];
#pragma unroll
            for (int nt = 0; nt < 4; nt++) bf[nt] = *(const short8*)&sm.ab.B[wc * 64 + nt * 16 + m][kk * 32 + g * 8];
#pragma unroll
            for (int mt = 0; mt < 4; mt++)
#pragma unroll
                for (int nt = 0; nt < 4; nt++)
                    acc[mt][nt] = __builtin_amdgcn_mfma_f32_16x16x32_bf16(af[mt], bf[nt], acc[mt][nt], 0, 0, 0);
        }
    }

    const int which = bx >> 1;
    const int h0 = (bx & 1) * 4;
    const int bidx = blockIdx.y >> 4;
    const int ntok0 = (blockIdx.y & 15) * 128;
    float bv[4];
#pragma unroll
    for (int nt = 0; nt < 4; nt++) bv[nt] = bias[bx * 128 + wc * 64 + nt * 16 + m];

    __syncthreads();
    if (which != 2) {
        const float qs = (which == 0) ? SCALE_LOG2E : 1.0f;
#pragma unroll
        for (int mt = 0; mt < 4; mt++)
#pragma unroll
            for (int nt = 0; nt < 4; nt++)
#pragma unroll
                for (int r = 0; r < 4; r++)
                    sm.C[wr * 64 + mt * 16 + g * 4 + r][wc * 64 + nt * 16 + m] =
                        f2bf((acc[mt][nt][r] + bv[nt]) * qs);
        __syncthreads();
        short* dst = (which == 0) ? Q : Kd;
        const int tok = tid >> 1, d0 = (tid & 1) * 16;
#pragma unroll
        for (int hh = 0; hh < 4; hh++) {
            size_t o = ((size_t)((bidx * NHEADS + h0 + hh) * SEQ) + ntok0 + tok) * HDIM + d0;
            *(short8*)&dst[o] = *(const short8*)&sm.C[tok][hh * 32 + d0];
            *(short8*)&dst[o + 8] = *(const short8*)&sm.C[tok][hh * 32 + d0 + 8];
        }
    } else {
#pragma unroll
        for (int mt = 0; mt < 4; mt++)
#pragma unroll
            for (int nt = 0; nt < 4; nt++) {
                uint2 p;
                p.x = pk2bf(acc[mt][nt][0] + bv[nt], acc[mt][nt][1] + bv[nt]);
                p.y = pk2bf(acc[mt][nt][2] + bv[nt], acc[mt][nt][3] + bv[nt]);
                *(uint2*)&sm.C[wc * 64 + nt * 16 + m][wr * 64 + mt * 16 + g * 4] = p;
            }
        __syncthreads();
        const int col = tid >> 1, t0 = (tid & 1) * 64;
        const int hh = col >> 5, d = col & 31;
        size_t o = ((size_t)((bidx * NHEADS + h0 + hh) * HDIM) + d) * SEQ + ntok0 + t0;
#pragma unroll
        for (int c2 = 0; c2 < 8; c2++)
            *(short8*)&V[o + c2 * 8] = *(const short8*)&sm.C[col][t0 + c2 * 8];
    }
}

// ---------------------------------------------------------------------------
// Attention: 64 q-rows/block, KV tile 128, k split across 4 waves (32 each).
// Double-buffered LDS; K stored sigma-permuted; P register-local; O/l
// reduced across waves through unioned LDS epilogue.
// ---------------------------------------------------------------------------
__global__ __launch_bounds__(256) void attn_tile(const short* __restrict__ Q,
                                                 const short* __restrict__ K,
                                                 const short* __restrict__ V,  // [bh][d][tok]
                                                 short* __restrict__ Zb) {
    __shared__ __align__(16) union SM {
        struct { short Ks[2][128][40]; short Vs[2][32][136]; } kv;   // 37888 B
        struct { float O[4][64][36]; float L[4][64]; } ep;           // 37888 B
    } sm;

    const int bh = blockIdx.y;
    const int b = bh >> 3, h = bh & 7;
    const int q0 = blockIdx.x * 64;
    const short* qb = Q + (size_t)bh * SEQ * HDIM;
    const short* kb = K + (size_t)bh * SEQ * HDIM;
    const short* vb = V + (size_t)bh * HDIM * SEQ;
    const int tid = threadIdx.x;
    const int w = tid >> 6, lane = tid & 63;
    const int m = lane & 15, g = lane >> 4;

    // Loop-invariant Q B-fragments (16B/lane, coalesced within each qt).
    short8 qfr[4];
#pragma unroll
    for (int qt = 0; qt < 4; qt++)
        qfr[qt] = *(const short8*)(qb + (size_t)(q0 + qt * 16 + m) * HDIM + g * 8);

    // K staging: thread -> tile row (tid>>1), col half (tid&1)*16; stored at
    // sigma-permuted LDS row so frag reads are contiguous: lambda(row).
    const int krow = tid >> 1, kcol = (tid & 1) * 16;
    const int rl = krow & 31;
    const int lrow = (krow & ~31) | (((rl >> 2) & 1) << 4) | ((rl >> 3) << 2) | (rl & 3);
    // V staging: thread -> d-row (tid>>3), col (tid&7)*16.
    const int vrow = tid >> 3, vcol = (tid & 7) * 16;

    f32x4 o[4][2] = {};
    f32x4 ol[4] = {};
    const short8 ones = {0x3F80, 0x3F80, 0x3F80, 0x3F80, 0x3F80, 0x3F80, 0x3F80, 0x3F80};

    short8 k0a = *(const short8*)(kb + (size_t)krow * HDIM + kcol);
    short8 k0b = *(const short8*)(kb + (size_t)krow * HDIM + kcol + 8);
    short8 v0a = *(const short8*)(vb + (size_t)vrow * SEQ + vcol);
    short8 v0b = *(const short8*)(vb + (size_t)vrow * SEQ + vcol + 8);
    *(short8*)&sm.kv.Ks[0][lrow][kcol] = k0a;
    *(short8*)&sm.kv.Ks[0][lrow][kcol + 8] = k0b;
    *(short8*)&sm.kv.Vs[0][vrow][vcol] = v0a;
    *(short8*)&sm.kv.Vs[0][vrow][vcol + 8] = v0b;
    __syncthreads();

    for (int it = 0; it < SEQ / 128; ++it) {
        const int buf = it & 1;
        if (it < SEQ / 128 - 1) {
            const int kn = (it + 1) * 128;
            k0a = *(const short8*)(kb + (size_t)(kn + krow) * HDIM + kcol);
            k0b = *(const short8*)(kb + (size_t)(kn + krow) * HDIM + kcol + 8);
            v0a = *(const short8*)(vb + (size_t)vrow * SEQ + kn + vcol);
            v0b = *(const short8*)(vb + (size_t)vrow * SEQ + kn + vcol + 8);
        }

        // Per-wave fragments: K rows w*32 + t*16 + m (permuted store), V^T.
        short8 kf0 = *(const short8*)&sm.kv.Ks[buf][w * 32 + m][g * 8];
        short8 kf1 = *(const short8*)&sm.kv.Ks[buf][w * 32 + 16 + m][g * 8];
        short8 vf0 = *(const short8*)&sm.kv.Vs[buf][m][w * 32 + g * 8];
        short8 vf1 = *(const short8*)&sm.kv.Vs[buf][16 + m][w * 32 + g * 8];

#pragma unroll
        for (int qt = 0; qt < 4; qt++) {
            f32x4 z4 = {0.f, 0.f, 0.f, 0.f};
            f32x4 st0 = __builtin_amdgcn_mfma_f32_16x16x32_bf16(kf0, qfr[qt], z4, 0, 0, 0);
            f32x4 st1 = __builtin_amdgcn_mfma_f32_16x16x32_bf16(kf1, qfr[qt], z4, 0, 0, 0);
            BF8 a;
            a.u[0] = pk2bf(__builtin_amdgcn_exp2f(st0[0]), __builtin_amdgcn_exp2f(st0[1]));
            a.u[1] = pk2bf(__builtin_amdgcn_exp2f(st0[2]), __builtin_amdgcn_exp2f(st0[3]));
            a.u[2] = pk2bf(__builtin_amdgcn_exp2f(st1[0]), __builtin_amdgcn_exp2f(st1[1]));
            a.u[3] = pk2bf(__builtin_amdgcn_exp2f(st1[2]), __builtin_amdgcn_exp2f(st1[3]));
            o[qt][0] = __builtin_amdgcn_mfma_f32_16x16x32_bf16(a.s8, vf0, o[qt][0], 0, 0, 0);
            o[qt][1] = __builtin_amdgcn_mfma_f32_16x16x32_bf16(a.s8, vf1, o[qt][1], 0, 0, 0);
            ol[qt] = __builtin_amdgcn_mfma_f32_16x16x32_bf16(a.s8, ones, ol[qt], 0, 0, 0);
        }

        if (it < SEQ / 128 - 1) {
            const int nb = buf ^ 1;
            *(short8*)&sm.kv.Ks[nb][lrow][kcol] = k0a;
            *(short8*)&sm.kv.Ks[nb][lrow][kcol + 8] = k0b;
            *(short8*)&sm.kv.Vs[nb][vrow][vcol] = v0a;
            *(short8*)&sm.kv.Vs[nb][vrow][vcol + 8] = v0b;
        }
        __syncthreads();
    }

    // Cross-wave reduction epilogue (LDS reused; all compute done).
#pragma unroll
    for (int qt = 0; qt < 4; qt++) {
#pragma unroll
        for (int dh = 0; dh < 2; dh++)
#pragma unroll
            for (int r = 0; r < 4; r++)
                sm.ep.O[w][qt * 16 + g * 4 + r][dh * 16 + m] = o[qt][dh][r];
        if (m == 0)
#pragma unroll
            for (int r = 0; r < 4; r++)
                sm.ep.L[w][qt * 16 + g * 4 + r] = ol[qt][r];
    }
    __syncthreads();

    const int ql = tid >> 2, d0 = (tid & 3) * 8;
    float lt = sm.ep.L[0][ql] + sm.ep.L[1][ql] + sm.ep.L[2][ql] + sm.ep.L[3][ql];
    float inv = __builtin_amdgcn_rcpf(lt);
    float sv[8];
#pragma unroll
    for (int j = 0; j < 8; j++)
        sv[j] = sm.ep.O[0][ql][d0 + j] + sm.ep.O[1][ql][d0 + j] +
                sm.ep.O[2][ql][d0 + j] + sm.ep.O[3][ql][d0 + j];
    BF8 pz;
#pragma unroll
    for (int j = 0; j < 4; j++)
        pz.u[j] = pk2bf(sv[2 * j] * inv, sv[2 * j + 1] * inv);
    *(short8*)&Zb[(size_t)(b * SEQ + q0 + ql) * DIMC + h * HDIM + d0] = pz.s8;
}

// ---------------------------------------------------------------------------
// Out GEMM (R3 version): 128x64 tile, BK=64, LDS-staged.
// ---------------------------------------------------------------------------
__global__ __launch_bounds__(256) void out_mfma(const short* __restrict__ A,
                                                const short* __restrict__ Wb,
                                                const float* __restrict__ bias,
                                                float* __restrict__ C) {
    __shared__ __align__(16) short As[128][72];
    __shared__ __align__(16) short Bs[64][72];
    const int m0 = blockIdx.y * 128, n0 = blockIdx.x * 64;
    const int tid = threadIdx.x;
    const int w = tid >> 6, lane = tid & 63;
    const int m = lane & 15, g = lane >> 4;
    const int wr = w >> 1, wc = w & 1;
    const int arow = tid >> 1, acol = (tid & 1) * 32;
    const int brow = tid >> 2, bcol = (tid & 3) * 16;

    f32x4 acc[4][2] = {};

    for (int kt = 0; kt < DIMC; kt += 64) {
        short8 a8[4], b8[2];
#pragma unroll
        for (int i = 0; i < 4; i++)
            a8[i] = *(const short8*)&A[(size_t)(m0 + arow) * DIMC + kt + acol + i * 8];
#pragma unroll
        for (int i = 0; i < 2; i++)
            b8[i] = *(const short8*)&Wb[(size_t)(n0 + brow) * DIMC + kt + bcol + i * 8];
        __syncthreads();
#pragma unroll
        for (int i = 0; i < 4; i++) *(short8*)&As[arow][acol + i * 8] = a8[i];
#pragma unroll
        for (int i = 0; i < 2; i++) *(short8*)&Bs[brow][bcol + i * 8] = b8[i];
        __syncthreads();
#pragma unroll
        for (int kk = 0; kk < 2; kk++) {
            short8 af[4], bf2[2];
#pragma unroll
            for (int mt = 0; mt < 4; mt++) af[mt] = *(const short8*)&As[wr * 64 + mt * 16 + m][kk * 32 + g * 8];
#pragma unroll
            for (int nt = 0; nt < 2; nt++) bf2[nt] = *(const short8*)&Bs[wc * 32 + nt * 16 + m][kk * 32 + g * 8];
#pragma unroll
            for (int mt = 0; mt < 4; mt++)
#pragma unroll
                for (int nt = 0; nt < 2; nt++)
                    acc[mt][nt] = __builtin_amdgcn_mfma_f32_16x16x32_bf16(af[mt], bf2[nt], acc[mt][nt], 0, 0, 0);
        }
    }

    float bv[2];
    bv[0] = bias[n0 + wc * 32 + m];
    bv[1] = bias[n0 + wc * 32 + 16 + m];
#pragma unroll
    for (int mt = 0; mt < 4; mt++)
#pragma unroll
        for (int nt = 0; nt < 2; nt++)
#pragma unroll
            for (int r = 0; r < 4; r++)
                C[(size_t)(m0 + wr * 64 + mt * 16 + g * 4 + r) * DIMC + n0 + wc * 32 + nt * 16 + m] =
                    acc[mt][nt][r] + bv[nt];
}

extern "C" void kernel_launch(void* const* d_in, const int* in_sizes, int n_in,
                              void* d_out, int out_size, void* d_ws, size_t ws_size,
                              hipStream_t stream) {
    const float* x     = (const float*)d_in[0];
    const float* w_qkv = (const float*)d_in[1];
    const float* b_qkv = (const float*)d_in[2];
    const float* w_out = (const float*)d_in[3];
    const float* b_out = (const float*)d_in[4];
    float* out = (float*)d_out;

    const size_t HSZ = (size_t)BATCH * NHEADS * SEQ * HDIM;
    short* xb  = (short*)d_ws;
    short* wqb = xb + NX;
    short* wob = wqb + NQW;
    short* qw  = wob + NOW;
    short* kw  = qw + HSZ;
    short* vw  = kw + HSZ;
    short* zb  = vw + HSZ;

    cvt_bf16<<<(NX + NQW + NOW) / 1024, 256, 0, stream>>>(x, w_qkv, w_out, xb, wqb, wob);
    qkv_mfma<<<dim3(6, 64), 256, 0, stream>>>(xb, wqb, b_qkv, qw, kw, vw);
    attn_tile<<<dim3(32, 32), 256, 0, stream>>>(qw, kw, vw, zb);
    out_mfma<<<dim3(4, 64), 256, 0, stream>>>(zb, wob, b_out, out);
}